// Round 6
// baseline (217.497 us; speedup 1.0000x reference)
//
#include <hip/hip_runtime.h>
#include <hip/hip_bf16.h>
#include <cstdint>
#include <cstddef>

#define B_   2
#define N_   6
#define FD_  128
#define DIM_ 128
#define H_   64
#define W_   176
#define P_   (H_*W_)      // 11264
#define IMGW 704.0
#define IMGH 256.0
#define UVB  8            // uv blocks per (b,n)

struct __align__(16) Samp { float wx, wy; int o00, o01; int o10, o11; int valid, pad; };

typedef __attribute__((ext_vector_type(8))) short short8;
typedef __attribute__((ext_vector_type(4))) float f32x4;

__device__ __forceinline__ float wave_sum(float v) {
#pragma unroll
  for (int off = 32; off > 0; off >>= 1) v += __shfl_xor(v, off, 64);
  return v;
}

// bf16 convert via HW cvt (compiler fuses pairs into v_cvt_pk_bf16_f32)
__device__ __forceinline__ unsigned short f2bf(float f) {
  union { __hip_bfloat16 h; unsigned short u; } c;
  c.h = __float2bfloat16(f);
  return c.u;
}
__device__ __forceinline__ float bf2f(unsigned short s) {
  return __uint_as_float(((unsigned int)s) << 16);
}

// ---------------- Kernel A: fp64 homography -> sample descriptors; BN fold; weight pre-swizzles ----------------
// blocks 0..95: uv work (8 blocks per bn). blocks 96..135: wprep — 160 frags x 64 lanes, single bf16:
//   f in [0,64): w1b, f in [64,128): w2b, f in [128,160): cwb (conv weights).
__global__ __launch_bounds__(256) void prep_kernel(const float* __restrict__ I_src, const float* __restrict__ I_tar_inv,
                           const float* __restrict__ E, const float* __restrict__ dis,
                           const float* __restrict__ nrm,
                           const float* __restrict__ bn_g, const float* __restrict__ bn_b,
                           const float* __restrict__ bn_m, const float* __restrict__ bn_v,
                           const float* __restrict__ w1, const float* __restrict__ w2,
                           const float* __restrict__ conv_w,
                           Samp* __restrict__ samp, float* __restrict__ bns, float* __restrict__ bnb,
                           short* __restrict__ w1b, short* __restrict__ w2b, short* __restrict__ cwb) {
  int blk = blockIdx.x;
  if (blk >= B_ * N_ * UVB) {
    int tid = (blk - B_ * N_ * UVB) * 256 + threadIdx.x;   // 0..10239
    int f = tid >> 6, l = tid & 63;
    if (f < 64) {
      int nt = f >> 2, ks = f & 3;
      int n = nt * 16 + (l & 15);
      int kb = ks * 32 + (l >> 4) * 8;
#pragma unroll
      for (int j = 0; j < 8; ++j)
        w1b[((size_t)f * 64 + l) * 8 + j] = (short)f2bf(w1[(size_t)(kb + j) * 256 + n]);
    } else if (f < 128) {
      int g = f - 64;
      int nt = g >> 3, ks = g & 7;
      int n = nt * 16 + (l & 15);
      int kb = ks * 32 + (l >> 4) * 8;
#pragma unroll
      for (int j = 0; j < 8; ++j)
        w2b[((size_t)g * 64 + l) * 8 + j] = (short)f2bf(w2[(size_t)(kb + j) * 128 + n]);
    } else {
      int g2 = f - 128;              // 0..31 -> (ot, ks) for conv frags
      int ot = g2 >> 2, ks = g2 & 3;
      int o  = ot * 16 + (l & 15);
      int cb = ks * 32 + (l >> 4) * 8;
#pragma unroll
      for (int j = 0; j < 8; ++j)
        cwb[((size_t)g2 * 64 + l) * 8 + j] = (short)f2bf(conv_w[(size_t)o * FD_ + cb + j]);
    }
    return;
  }
  int bn = blk / UVB;             // 0..11
  int part = blk % UVB;           // 0..7
  int bb = bn / N_;
  if (blk == 0 && threadIdx.x < FD_) {
    int t = threadIdx.x;
    float inv = 1.0f / sqrtf(bn_v[t] + 1e-5f);
    float sc = bn_g[t] * inv;
    bns[t] = sc;
    bnb[t] = bn_b[t] - bn_m[t] * sc;
  }
  const float* Ep = E + bn * 16;
  double R[9], T[3];
#pragma unroll
  for (int i = 0; i < 3; ++i) {
#pragma unroll
    for (int j = 0; j < 3; ++j) R[i*3+j] = (double)Ep[i*4+j];
    T[i] = (double)Ep[i*4+3];
  }
  double dd = (double)dis[bb];
  double M[9];
#pragma unroll
  for (int i = 0; i < 3; ++i)
#pragma unroll
    for (int j = 0; j < 3; ++j)
      M[i*3+j] = R[i*3+j] - T[i] * (double)nrm[bb*3+j] / dd;
  const float* Is = I_src + bn * 9;
  double A[9];
#pragma unroll
  for (int i = 0; i < 3; ++i)
#pragma unroll
    for (int j = 0; j < 3; ++j)
      A[i*3+j] = (double)Is[i*3+0]*M[0+j] + (double)Is[i*3+1]*M[3+j] + (double)Is[i*3+2]*M[6+j];
  const float* It = I_tar_inv + bb * 9;
  double Hm[9];
#pragma unroll
  for (int i = 0; i < 3; ++i)
#pragma unroll
    for (int j = 0; j < 3; ++j)
      Hm[i*3+j] = A[i*3+0]*(double)It[0+j] + A[i*3+1]*(double)It[3+j] + A[i*3+2]*(double)It[6+j];

  const double dx = 1.0 / (double)(W_ - 1);
  const double dy = 1.0 / (double)(H_ - 1);
  for (int p = part * 256 + threadIdx.x; p < P_; p += 256 * UVB) {
    int ii = p / W_;
    int jj = p - ii * W_;
    double xs = (jj == W_ - 1) ? 1.0 : (double)jj * dx;   // np.linspace exact endpoint
    double ys = (ii == H_ - 1) ? 1.0 : (double)ii * dy;
    double px = xs * IMGW;
    double py = ys * IMGH;
    double hx = Hm[0]*px + Hm[1]*py + Hm[2];
    double hy = Hm[3]*px + Hm[4]*py + Hm[5];
    double hz = Hm[6]*px + Hm[7]*py + Hm[8];
    double u = ((hx / hz) / IMGW) * (double)W_;
    double v = ((hy / hz) / IMGH) * (double)H_;
    double x0 = floor(u), y0 = floor(v);
    bool valid = (u >= 0.0) && (u <= (double)(W_ - 1)) && (v >= 0.0) && (v <= (double)(H_ - 1));
    int x0i = min(max((int)x0, 0), W_ - 1);
    int x1i = min(x0i + 1, W_ - 1);
    int y0i = min(max((int)y0, 0), H_ - 1);
    int y1i = min(y0i + 1, H_ - 1);
    Samp s;
    s.wx = (float)(u - x0);
    s.wy = (float)(v - y0);
    s.o00 = (y0i * W_ + x0i) * DIM_;
    s.o01 = (y0i * W_ + x1i) * DIM_;
    s.o10 = (y1i * W_ + x0i) * DIM_;
    s.o11 = (y1i * W_ + x1i) * DIM_;
    s.valid = valid ? 1 : 0;
    s.pad = 0;
    samp[(size_t)bn * P_ + p] = s;
  }
}

// ---------------- Kernel B: BN+ReLU+1x1 conv as bf16 MFMA -> val_t[bn][p][o] in BF16 ----------------
// No-LDS variant: A-fragments loaded DIRECTLY from global feature, BN+ReLU+hi/lo split in registers.
// Weights (cwb, pre-swizzled bf16, 32 KB, L1-resident) as B operand; round-0 store pattern.
__global__ __launch_bounds__(256) void conv_kernel(const float* __restrict__ feature,
    const short* __restrict__ cwb, const float* __restrict__ bns_g, const float* __restrict__ bnb_g,
    unsigned short* __restrict__ val_t) {
  __shared__ float bns_s[FD_], bnb_s[FD_];
  int t = threadIdx.x;
  if (t < FD_) { bns_s[t] = bns_g[t]; bnb_s[t] = bnb_g[t]; }
  __syncthreads();

  int bn = blockIdx.y;
  int p0 = blockIdx.x * 64;
  int lane = t & 63, wv = t >> 6;
  int m = lane & 15, quad = lane >> 4;
  int pw = wv * 16;

  const float* fb = feature + (size_t)bn * FD_ * P_ + p0 + pw + m;

  float xv[4][8];
#pragma unroll
  for (int ks = 0; ks < 4; ++ks)
#pragma unroll
    for (int j = 0; j < 8; ++j) {
      int c = ks * 32 + quad * 8 + j;
      xv[ks][j] = fb[(size_t)c * P_];
    }

  short8 Ah[4], Al[4];
#pragma unroll
  for (int ks = 0; ks < 4; ++ks)
#pragma unroll
    for (int j = 0; j < 8; ++j) {
      int c = ks * 32 + quad * 8 + j;
      float v = fmaxf(xv[ks][j] * bns_s[c] + bnb_s[c], 0.f);
      unsigned short h = f2bf(v);
      Ah[ks][j] = (short)h;
      Al[ks][j] = (short)f2bf(v - bf2f(h));
    }

  f32x4 acc[8];
#pragma unroll
  for (int ot = 0; ot < 8; ++ot) {
    f32x4 a = {0.f, 0.f, 0.f, 0.f};
#pragma unroll
    for (int ks = 0; ks < 4; ++ks) {
      short8 Bv = *(const short8*)(cwb + ((size_t)(ot * 4 + ks) * 64 + lane) * 8);
      a = __builtin_amdgcn_mfma_f32_16x16x32_bf16(Ah[ks], Bv, a, 0, 0, 0);
      a = __builtin_amdgcn_mfma_f32_16x16x32_bf16(Al[ks], Bv, a, 0, 0, 0);
    }
    acc[ot] = a;
  }

  unsigned short* vb = val_t + ((size_t)bn * P_ + p0 + pw + quad * 4) * DIM_ + m;
#pragma unroll
  for (int ot = 0; ot < 8; ++ot)
#pragma unroll
    for (int r = 0; r < 4; ++r)
      vb[(size_t)r * DIM_ + ot * 16] = f2bf(acc[ot][r]);
}

// ---------------- Kernel C: warp-per-point bilinear attention + LN1 (bf16 val_t, XCD swizzle) ----------------
__global__ __launch_bounds__(256) void attn_kernel(const unsigned short* __restrict__ val_t,
    const Samp* __restrict__ samp,
    const float* __restrict__ ln1g, const float* __restrict__ ln1b,
    float* __restrict__ zln) {
  int lane = threadIdx.x & 63;
  int wv = threadIdx.x >> 6;
  int bid = blockIdx.x;
  int newbid = (bid & 7) * (gridDim.x >> 3) + (bid >> 3);
  int pt = newbid * 4 + wv;
  if (pt >= B_ * P_) return;
  int bb = pt / P_;
  int p = pt - bb * P_;
  int d0 = lane << 1;

  unsigned int uq = *(const unsigned int*)(val_t + ((size_t)(bb * N_) * P_ + p) * DIM_ + d0);
  float qx = bf2f((unsigned short)(uq & 0xffffu));
  float qy = bf2f((unsigned short)(uq >> 16));
  float qss = wave_sum(qx * qx + qy * qy);
  float qinv = 1.0f / fmaxf(sqrtf(qss), 1e-12f);

  float dots[N_], vs0[N_], vs1[N_];
#pragma unroll
  for (int n = 0; n < N_; ++n) {
    Samp s = samp[(size_t)(bb * N_ + n) * P_ + p];
    const unsigned short* base = val_t + (size_t)(bb * N_ + n) * P_ * DIM_ + d0;
    unsigned int u00 = *(const unsigned int*)(base + s.o00);
    unsigned int u01 = *(const unsigned int*)(base + s.o01);
    unsigned int u10 = *(const unsigned int*)(base + s.o10);
    unsigned int u11 = *(const unsigned int*)(base + s.o11);
    float wx = s.wx, wy = s.wy;
    float w00 = (1.0f - wx) * (1.0f - wy), w01 = wx * (1.0f - wy);
    float w10 = (1.0f - wx) * wy,          w11 = wx * wy;
    float v0 = bf2f((unsigned short)(u00 & 0xffffu)) * w00 + bf2f((unsigned short)(u01 & 0xffffu)) * w01
             + bf2f((unsigned short)(u10 & 0xffffu)) * w10 + bf2f((unsigned short)(u11 & 0xffffu)) * w11;
    float v1 = bf2f((unsigned short)(u00 >> 16)) * w00 + bf2f((unsigned short)(u01 >> 16)) * w01
             + bf2f((unsigned short)(u10 >> 16)) * w10 + bf2f((unsigned short)(u11 >> 16)) * w11;
    // joint butterfly: ||v||^2 and q.v in one pass (dot = qinv*kinv*sum(q*v))
    float ss = v0 * v0 + v1 * v1;
    float du = qx * v0 + qy * v1;
#pragma unroll
    for (int off = 32; off > 0; off >>= 1) {
      ss += __shfl_xor(ss, off, 64);
      du += __shfl_xor(du, off, 64);
    }
    float kinv = 1.0f / fmaxf(sqrtf(ss), 1e-12f);
    dots[n] = s.valid ? (du * kinv * qinv) : 0.0f;
    vs0[n] = v0; vs1[n] = v1;
  }
  float mx = dots[0];
#pragma unroll
  for (int n = 1; n < N_; ++n) mx = fmaxf(mx, dots[n]);
  float es[N_], den = 0.f;
#pragma unroll
  for (int n = 0; n < N_; ++n) { es[n] = expf(dots[n] - mx); den += es[n]; }
  float dinv = 1.0f / den;
  float z0 = qx, z1 = qy;
#pragma unroll
  for (int n = 0; n < N_; ++n) { float a = es[n] * dinv; z0 += a * vs0[n]; z1 += a * vs1[n]; }
  float mean = wave_sum(z0 + z1) * (1.0f / DIM_);
  float c0 = z0 - mean, c1 = z1 - mean;
  float var = wave_sum(c0 * c0 + c1 * c1) * (1.0f / DIM_);
  float rstd = rsqrtf(var + 1e-5f);
  float o0 = c0 * rstd * ln1g[d0]     + ln1b[d0];
  float o1 = c1 * rstd * ln1g[d0 + 1] + ln1b[d0 + 1];
  *(float2*)(zln + (size_t)pt * DIM_ + d0) = make_float2(o0, o1);
}

// ---------------- Kernel D: MLP — INDEPENDENT-WAVE design. 16 px per wave, 64-thr blocks, 1408 blocks ----
// No block-wide synchronization pressure: each wave owns its 16 rows end-to-end; LDS is wave-private
// (hdn hi/lo planes [16][264] shorts = 16896 B; zo [128][20] floats overlays after). __syncthreads in a
// single-wave block is wave-local (cheap) and only orders LDS aliasing. LN2 fully in-register via
// shfl_xor(1,2,4,8) (m-lane reduction; quad-invariant). GEMM work per px unchanged (256 MFMA / 16 px).
__global__ __launch_bounds__(64) void mlp_kernel(const float* __restrict__ zln,
    const short* __restrict__ w1b, const short* __restrict__ w2b,
    const float* __restrict__ b1, const float* __restrict__ b2,
    const float* __restrict__ ln2g, const float* __restrict__ ln2b,
    float* __restrict__ out) {
  __shared__ __align__(16) char smem[16896];
  short* hh = (short*)smem;             // [16][264] shorts, 8448 B
  short* hl = (short*)(smem + 8448);    // [16][264] shorts, 8448 B
  float* zo = (float*)smem;             // [128][20] floats, 10240 B (overlay, after hdn dead)

  int l = threadIdx.x;                  // 0..63
  int m = l & 15, quad = l >> 4;
  int row0 = blockIdx.x * 16;

  // ---- A1 fragments direct from global zln (hi/lo split) ----
  const float* zr0 = zln + (size_t)(row0 + m) * DIM_;
  short8 A1h[4], A1l[4];
#pragma unroll
  for (int ks = 0; ks < 4; ++ks) {
    float4 xa = *(const float4*)(zr0 + ks * 32 + quad * 8);
    float4 xb = *(const float4*)(zr0 + ks * 32 + quad * 8 + 4);
    float v[8] = {xa.x, xa.y, xa.z, xa.w, xb.x, xb.y, xb.z, xb.w};
#pragma unroll
    for (int j = 0; j < 8; ++j) {
      unsigned short h = f2bf(v[j]);
      A1h[ks][j] = (short)h;
      A1l[ks][j] = (short)f2bf(v[j] - bf2f(h));
    }
  }

  // residual: res[dt][r] = zln[row0 + quad*4 + r][dt*16 + m]  (16-lane coalesced per (dt,r))
  float res[8][4];
#pragma unroll
  for (int dt = 0; dt < 8; ++dt)
#pragma unroll
    for (int r = 0; r < 4; ++r)
      res[dt][r] = zln[(size_t)(row0 + quad * 4 + r) * DIM_ + dt * 16 + m];

  float b1v[16];
#pragma unroll
  for (int nt = 0; nt < 16; ++nt) b1v[nt] = b1[nt * 16 + m];
  float b2v[8], g2v[8], be2v[8];
#pragma unroll
  for (int dt = 0; dt < 8; ++dt) {
    int d = dt * 16 + m;
    b2v[dt] = b2[d]; g2v[dt] = ln2g[d]; be2v[dt] = ln2b[d];
  }

  // ---- GEMM1: hdn[16px][256] = gelu(zl @ w1 + b1), hi/lo bf16 into wave-private LDS ----
#pragma unroll
  for (int nt = 0; nt < 16; ++nt) {
    f32x4 a = {0.f, 0.f, 0.f, 0.f};
#pragma unroll
    for (int ks = 0; ks < 4; ++ks) {
      short8 Bv = *(const short8*)(w1b + ((size_t)(nt * 4 + ks) * 64 + l) * 8);
      a = __builtin_amdgcn_mfma_f32_16x16x32_bf16(A1h[ks], Bv, a, 0, 0, 0);
      a = __builtin_amdgcn_mfma_f32_16x16x32_bf16(A1l[ks], Bv, a, 0, 0, 0);
    }
#pragma unroll
    for (int r = 0; r < 4; ++r) {
      float hv = a[r] + b1v[nt];
      float g = 0.5f * hv * (1.0f + erff(hv * 0.70710678118654752f));
      unsigned short gh = f2bf(g);
      int addr = (quad * 4 + r) * 264 + nt * 16 + m;
      hh[addr] = (short)gh;
      hl[addr] = (short)f2bf(g - bf2f(gh));
    }
  }
  __syncthreads();   // wave-local: order hdn writes before reads

  // ---- GEMM2: z2[16px][128] = hdn @ w2 ----
  f32x4 acc2[8];
#pragma unroll
  for (int dt = 0; dt < 8; ++dt) acc2[dt] = (f32x4){0.f, 0.f, 0.f, 0.f};
#pragma unroll
  for (int ks2 = 0; ks2 < 8; ++ks2) {
    short8 A2h = *(const short8*)&hh[m * 264 + ks2 * 32 + quad * 8];
    short8 A2l = *(const short8*)&hl[m * 264 + ks2 * 32 + quad * 8];
#pragma unroll
    for (int dt = 0; dt < 8; ++dt) {
      short8 Bv = *(const short8*)(w2b + ((size_t)(dt * 8 + ks2) * 64 + l) * 8);
      acc2[dt] = __builtin_amdgcn_mfma_f32_16x16x32_bf16(A2h, Bv, acc2[dt], 0, 0, 0);
      acc2[dt] = __builtin_amdgcn_mfma_f32_16x16x32_bf16(A2l, Bv, acc2[dt], 0, 0, 0);
    }
  }

  // bias + residual
  float z2[8][4];
#pragma unroll
  for (int dt = 0; dt < 8; ++dt)
#pragma unroll
    for (int r = 0; r < 4; ++r)
      z2[dt][r] = acc2[dt][r] + b2v[dt] + res[dt][r];

  // ---- LN2 fully in-register: reduce over d = (dt, m); shfl_xor(1,2,4,8) keeps quad invariant ----
  float mean[4], rstd[4];
#pragma unroll
  for (int r = 0; r < 4; ++r) {
    float s = 0.f, q2 = 0.f;
#pragma unroll
    for (int dt = 0; dt < 8; ++dt) { float z = z2[dt][r]; s += z; q2 += z * z; }
#pragma unroll
    for (int off = 1; off <= 8; off <<= 1) {
      s  += __shfl_xor(s,  off, 64);
      q2 += __shfl_xor(q2, off, 64);
    }
    mean[r] = s * (1.0f / 128.0f);
    float var = fmaxf(q2 * (1.0f / 128.0f) - mean[r] * mean[r], 0.f);
    rstd[r] = rsqrtf(var + 1e-5f);
  }
  __syncthreads();   // wave-local: hdn reads done before zo overlay

  // ---- transpose via wave-private zo[128][20], then coalesced float4 stores ----
#pragma unroll
  for (int dt = 0; dt < 8; ++dt)
#pragma unroll
    for (int r = 0; r < 4; ++r) {
      float v = (z2[dt][r] - mean[r]) * rstd[r] * g2v[dt] + be2v[dt];
      zo[(dt * 16 + m) * 20 + quad * 4 + r] = v;
    }
  __syncthreads();   // wave-local

  int bb2 = row0 / P_;
  int p0 = row0 - bb2 * P_;
  float* ob = out + (size_t)bb2 * DIM_ * P_ + p0;
#pragma unroll
  for (int pass = 0; pass < 8; ++pass) {
    int idx = pass * 64 + l;      // 0..511
    int d = idx >> 2, fq = idx & 3;
    float4 v4 = *(float4*)&zo[d * 20 + fq * 4];
    *(float4*)(ob + (size_t)d * P_ + fq * 4) = v4;
  }
}

extern "C" void kernel_launch(void* const* d_in, const int* in_sizes, int n_in,
                              void* d_out, int out_size, void* d_ws, size_t ws_size,
                              hipStream_t stream) {
  const float* feature = (const float*)d_in[0];
  const float* I_src   = (const float*)d_in[1];
  const float* I_tar   = (const float*)d_in[2];
  const float* E       = (const float*)d_in[3];
  const float* dis     = (const float*)d_in[4];
  const float* nrm     = (const float*)d_in[5];
  const float* conv_w  = (const float*)d_in[6];
  const float* bn_g    = (const float*)d_in[7];
  const float* bn_b    = (const float*)d_in[8];
  const float* bn_m    = (const float*)d_in[9];
  const float* bn_v    = (const float*)d_in[10];
  const float* ln1g    = (const float*)d_in[11];
  const float* ln1b    = (const float*)d_in[12];
  const float* ln2g    = (const float*)d_in[13];
  const float* ln2b    = (const float*)d_in[14];
  const float* w1      = (const float*)d_in[15];
  const float* b1      = (const float*)d_in[16];
  const float* w2      = (const float*)d_in[17];
  const float* b2      = (const float*)d_in[18];
  float* out = (float*)d_out;

  float* wsf = (float*)d_ws;
  float* bns = wsf;                   // 128
  float* bnb = wsf + 128;             // 128
  unsigned short* val_t = (unsigned short*)(wsf + 256);          // B*N*P*DIM bf16 (34.6 MB)
  float* zln = (float*)(val_t + (size_t)B_ * N_ * P_ * DIM_);    // B*P*DIM floats
  Samp*  samp = (Samp*)(zln + (size_t)B_ * P_ * DIM_);           // 12*P structs (32B each)
  short* w1b = (short*)(samp + (size_t)B_ * N_ * P_);            // 32768 shorts
  short* w2b = w1b + 32768;                                      // 32768 shorts
  short* cwb = w2b + 32768;                                      // 16384 shorts (conv frags)

  hipLaunchKernelGGL(prep_kernel, dim3(B_ * N_ * UVB + 40), dim3(256), 0, stream,
                     I_src, I_tar, E, dis, nrm, bn_g, bn_b, bn_m, bn_v, w1, w2, conv_w,
                     samp, bns, bnb, w1b, w2b, cwb);
  hipLaunchKernelGGL(conv_kernel, dim3(P_ / 64, B_ * N_), dim3(256), 0, stream,
                     feature, cwb, bns, bnb, val_t);
  hipLaunchKernelGGL(attn_kernel, dim3(B_ * P_ / 4), dim3(256), 0, stream,
                     val_t, samp, ln1g, ln1b, zln);
  hipLaunchKernelGGL(mlp_kernel, dim3(B_ * P_ / 16), dim3(64), 0, stream,
                     zln, w1b, w2b, b1, b2, ln2g, ln2b, out);
}

// Round 7
// 211.164 us; speedup vs baseline: 1.0300x; 1.0300x over previous
//
#include <hip/hip_runtime.h>
#include <hip/hip_bf16.h>
#include <cstdint>
#include <cstddef>

#define B_   2
#define N_   6
#define FD_  128
#define DIM_ 128
#define H_   64
#define W_   176
#define P_   (H_*W_)      // 11264
#define IMGW 704.0
#define IMGH 256.0
#define UVB  8            // uv blocks per (b,n)

struct __align__(16) Samp { float wx, wy; int o00, o01; int o10, o11; int valid, pad; };

typedef __attribute__((ext_vector_type(8))) short short8;
typedef __attribute__((ext_vector_type(4))) float f32x4;

__device__ __forceinline__ float wave_sum(float v) {
#pragma unroll
  for (int off = 32; off > 0; off >>= 1) v += __shfl_xor(v, off, 64);
  return v;
}

// bf16 convert via HW cvt (compiler fuses pairs into v_cvt_pk_bf16_f32)
__device__ __forceinline__ unsigned short f2bf(float f) {
  union { __hip_bfloat16 h; unsigned short u; } c;
  c.h = __float2bfloat16(f);
  return c.u;
}
__device__ __forceinline__ float bf2f(unsigned short s) {
  return __uint_as_float(((unsigned int)s) << 16);
}
__device__ __forceinline__ float bfx(uint2 u, int j) {   // j-th bf16 of an 8B pack (j compile-time)
  unsigned int w = (j < 2) ? u.x : u.y;
  return bf2f((unsigned short)((j & 1) ? (w >> 16) : (w & 0xffffu)));
}

// ---------------- Kernel A: fp64 homography -> sample descriptors; BN fold; weight pre-swizzles ----------------
// blocks 0..95: uv work (8 blocks per bn). blocks 96..135: wprep — 160 frags x 64 lanes, single bf16:
//   f in [0,64): w1b, f in [64,128): w2b, f in [128,160): cwb (conv weights).
__global__ __launch_bounds__(256) void prep_kernel(const float* __restrict__ I_src, const float* __restrict__ I_tar_inv,
                           const float* __restrict__ E, const float* __restrict__ dis,
                           const float* __restrict__ nrm,
                           const float* __restrict__ bn_g, const float* __restrict__ bn_b,
                           const float* __restrict__ bn_m, const float* __restrict__ bn_v,
                           const float* __restrict__ w1, const float* __restrict__ w2,
                           const float* __restrict__ conv_w,
                           Samp* __restrict__ samp, float* __restrict__ bns, float* __restrict__ bnb,
                           short* __restrict__ w1b, short* __restrict__ w2b, short* __restrict__ cwb) {
  int blk = blockIdx.x;
  if (blk >= B_ * N_ * UVB) {
    int tid = (blk - B_ * N_ * UVB) * 256 + threadIdx.x;   // 0..10239
    int f = tid >> 6, l = tid & 63;
    if (f < 64) {
      int nt = f >> 2, ks = f & 3;
      int n = nt * 16 + (l & 15);
      int kb = ks * 32 + (l >> 4) * 8;
#pragma unroll
      for (int j = 0; j < 8; ++j)
        w1b[((size_t)f * 64 + l) * 8 + j] = (short)f2bf(w1[(size_t)(kb + j) * 256 + n]);
    } else if (f < 128) {
      int g = f - 64;
      int nt = g >> 3, ks = g & 7;
      int n = nt * 16 + (l & 15);
      int kb = ks * 32 + (l >> 4) * 8;
#pragma unroll
      for (int j = 0; j < 8; ++j)
        w2b[((size_t)g * 64 + l) * 8 + j] = (short)f2bf(w2[(size_t)(kb + j) * 128 + n]);
    } else {
      int g2 = f - 128;              // 0..31 -> (ot, ks) for conv frags
      int ot = g2 >> 2, ks = g2 & 3;
      int o  = ot * 16 + (l & 15);
      int cb = ks * 32 + (l >> 4) * 8;
#pragma unroll
      for (int j = 0; j < 8; ++j)
        cwb[((size_t)g2 * 64 + l) * 8 + j] = (short)f2bf(conv_w[(size_t)o * FD_ + cb + j]);
    }
    return;
  }
  int bn = blk / UVB;             // 0..11
  int part = blk % UVB;           // 0..7
  int bb = bn / N_;
  if (blk == 0 && threadIdx.x < FD_) {
    int t = threadIdx.x;
    float inv = 1.0f / sqrtf(bn_v[t] + 1e-5f);
    float sc = bn_g[t] * inv;
    bns[t] = sc;
    bnb[t] = bn_b[t] - bn_m[t] * sc;
  }
  const float* Ep = E + bn * 16;
  double R[9], T[3];
#pragma unroll
  for (int i = 0; i < 3; ++i) {
#pragma unroll
    for (int j = 0; j < 3; ++j) R[i*3+j] = (double)Ep[i*4+j];
    T[i] = (double)Ep[i*4+3];
  }
  double dd = (double)dis[bb];
  double M[9];
#pragma unroll
  for (int i = 0; i < 3; ++i)
#pragma unroll
    for (int j = 0; j < 3; ++j)
      M[i*3+j] = R[i*3+j] - T[i] * (double)nrm[bb*3+j] / dd;
  const float* Is = I_src + bn * 9;
  double A[9];
#pragma unroll
  for (int i = 0; i < 3; ++i)
#pragma unroll
    for (int j = 0; j < 3; ++j)
      A[i*3+j] = (double)Is[i*3+0]*M[0+j] + (double)Is[i*3+1]*M[3+j] + (double)Is[i*3+2]*M[6+j];
  const float* It = I_tar_inv + bb * 9;
  double Hm[9];
#pragma unroll
  for (int i = 0; i < 3; ++i)
#pragma unroll
    for (int j = 0; j < 3; ++j)
      Hm[i*3+j] = A[i*3+0]*(double)It[0+j] + A[i*3+1]*(double)It[3+j] + A[i*3+2]*(double)It[6+j];

  const double dx = 1.0 / (double)(W_ - 1);
  const double dy = 1.0 / (double)(H_ - 1);
  for (int p = part * 256 + threadIdx.x; p < P_; p += 256 * UVB) {
    int ii = p / W_;
    int jj = p - ii * W_;
    double xs = (jj == W_ - 1) ? 1.0 : (double)jj * dx;   // np.linspace exact endpoint
    double ys = (ii == H_ - 1) ? 1.0 : (double)ii * dy;
    double px = xs * IMGW;
    double py = ys * IMGH;
    double hx = Hm[0]*px + Hm[1]*py + Hm[2];
    double hy = Hm[3]*px + Hm[4]*py + Hm[5];
    double hz = Hm[6]*px + Hm[7]*py + Hm[8];
    double u = ((hx / hz) / IMGW) * (double)W_;
    double v = ((hy / hz) / IMGH) * (double)H_;
    double x0 = floor(u), y0 = floor(v);
    bool valid = (u >= 0.0) && (u <= (double)(W_ - 1)) && (v >= 0.0) && (v <= (double)(H_ - 1));
    int x0i = min(max((int)x0, 0), W_ - 1);
    int x1i = min(x0i + 1, W_ - 1);
    int y0i = min(max((int)y0, 0), H_ - 1);
    int y1i = min(y0i + 1, H_ - 1);
    Samp s;
    s.wx = (float)(u - x0);
    s.wy = (float)(v - y0);
    s.o00 = (y0i * W_ + x0i) * DIM_;
    s.o01 = (y0i * W_ + x1i) * DIM_;
    s.o10 = (y1i * W_ + x0i) * DIM_;
    s.o11 = (y1i * W_ + x1i) * DIM_;
    s.valid = valid ? 1 : 0;
    s.pad = 0;
    samp[(size_t)bn * P_ + p] = s;
  }
}

// ---------------- Kernel B: BN+ReLU+1x1 conv as bf16 MFMA -> val_t[bn][p][o] in BF16 ----------------
// No-LDS variant: A-fragments loaded DIRECTLY from global feature, BN+ReLU+hi/lo split in registers.
// Weights (cwb, pre-swizzled bf16, 32 KB, L1-resident) as B operand; round-0 store pattern.
__global__ __launch_bounds__(256) void conv_kernel(const float* __restrict__ feature,
    const short* __restrict__ cwb, const float* __restrict__ bns_g, const float* __restrict__ bnb_g,
    unsigned short* __restrict__ val_t) {
  __shared__ float bns_s[FD_], bnb_s[FD_];
  int t = threadIdx.x;
  if (t < FD_) { bns_s[t] = bns_g[t]; bnb_s[t] = bnb_g[t]; }
  __syncthreads();

  int bn = blockIdx.y;
  int p0 = blockIdx.x * 64;
  int lane = t & 63, wv = t >> 6;
  int m = lane & 15, quad = lane >> 4;
  int pw = wv * 16;

  const float* fb = feature + (size_t)bn * FD_ * P_ + p0 + pw + m;

  float xv[4][8];
#pragma unroll
  for (int ks = 0; ks < 4; ++ks)
#pragma unroll
    for (int j = 0; j < 8; ++j) {
      int c = ks * 32 + quad * 8 + j;
      xv[ks][j] = fb[(size_t)c * P_];
    }

  short8 Ah[4], Al[4];
#pragma unroll
  for (int ks = 0; ks < 4; ++ks)
#pragma unroll
    for (int j = 0; j < 8; ++j) {
      int c = ks * 32 + quad * 8 + j;
      float v = fmaxf(xv[ks][j] * bns_s[c] + bnb_s[c], 0.f);
      unsigned short h = f2bf(v);
      Ah[ks][j] = (short)h;
      Al[ks][j] = (short)f2bf(v - bf2f(h));
    }

  f32x4 acc[8];
#pragma unroll
  for (int ot = 0; ot < 8; ++ot) {
    f32x4 a = {0.f, 0.f, 0.f, 0.f};
#pragma unroll
    for (int ks = 0; ks < 4; ++ks) {
      short8 Bv = *(const short8*)(cwb + ((size_t)(ot * 4 + ks) * 64 + lane) * 8);
      a = __builtin_amdgcn_mfma_f32_16x16x32_bf16(Ah[ks], Bv, a, 0, 0, 0);
      a = __builtin_amdgcn_mfma_f32_16x16x32_bf16(Al[ks], Bv, a, 0, 0, 0);
    }
    acc[ot] = a;
  }

  unsigned short* vb = val_t + ((size_t)bn * P_ + p0 + pw + quad * 4) * DIM_ + m;
#pragma unroll
  for (int ot = 0; ot < 8; ++ot)
#pragma unroll
    for (int r = 0; r < 4; ++r)
      vb[(size_t)r * DIM_ + ot * 16] = f2bf(acc[ot][r]);
}

// ---------------- Kernel C: bilinear attention + LN1 — 2 px per wave, 32-lane groups, 4 dims/lane ----
// half = lane>>5 selects px of the pair; sl = lane&31; d0 = sl*4. All reductions are 5-round
// shfl_xor(1..16) butterflies (never cross the 32-lane boundary). Corner loads widened to 8B uint2;
// every VMEM instruction serves 2 points. LN1 via joint (sum, sumsq) single reduction.
__global__ __launch_bounds__(256) void attn_kernel(const unsigned short* __restrict__ val_t,
    const Samp* __restrict__ samp,
    const float* __restrict__ ln1g, const float* __restrict__ ln1b,
    float* __restrict__ zln) {
  int lane = threadIdx.x & 63;
  int wv = threadIdx.x >> 6;
  int half = lane >> 5;
  int sl = lane & 31;
  int bid = blockIdx.x;
  int newbid = (bid & 7) * (gridDim.x >> 3) + (bid >> 3);   // XCD swizzle (grid % 8 == 0)
  int pt = newbid * 8 + wv * 2 + half;
  int bb = pt / P_;
  int p = pt - bb * P_;
  int d0 = sl << 2;               // dims d0..d0+3

  uint2 uq = *(const uint2*)(val_t + ((size_t)(bb * N_) * P_ + p) * DIM_ + d0);
  float qv[4] = { bfx(uq, 0), bfx(uq, 1), bfx(uq, 2), bfx(uq, 3) };
  float qss = qv[0]*qv[0] + qv[1]*qv[1] + qv[2]*qv[2] + qv[3]*qv[3];
#pragma unroll
  for (int off = 1; off <= 16; off <<= 1) qss += __shfl_xor(qss, off, 64);
  float qinv = 1.0f / fmaxf(sqrtf(qss), 1e-12f);

  float dots[N_], vs[N_][4];
#pragma unroll
  for (int n = 0; n < N_; ++n) {
    Samp s = samp[(size_t)(bb * N_ + n) * P_ + p];
    const unsigned short* base = val_t + (size_t)(bb * N_ + n) * P_ * DIM_ + d0;
    uint2 u00 = *(const uint2*)(base + s.o00);
    uint2 u01 = *(const uint2*)(base + s.o01);
    uint2 u10 = *(const uint2*)(base + s.o10);
    uint2 u11 = *(const uint2*)(base + s.o11);
    float wx = s.wx, wy = s.wy;
    float w00 = (1.0f - wx) * (1.0f - wy), w01 = wx * (1.0f - wy);
    float w10 = (1.0f - wx) * wy,          w11 = wx * wy;
    float ss = 0.f, du = 0.f;
#pragma unroll
    for (int j = 0; j < 4; ++j) {
      float v = bfx(u00, j) * w00 + bfx(u01, j) * w01 + bfx(u10, j) * w10 + bfx(u11, j) * w11;
      vs[n][j] = v;
      ss += v * v;
      du += qv[j] * v;
    }
#pragma unroll
    for (int off = 1; off <= 16; off <<= 1) {
      ss += __shfl_xor(ss, off, 64);
      du += __shfl_xor(du, off, 64);
    }
    float kinv = 1.0f / fmaxf(sqrtf(ss), 1e-12f);
    dots[n] = s.valid ? (du * kinv * qinv) : 0.0f;
  }
  float mx = dots[0];
#pragma unroll
  for (int n = 1; n < N_; ++n) mx = fmaxf(mx, dots[n]);
  float es[N_], den = 0.f;
#pragma unroll
  for (int n = 0; n < N_; ++n) { es[n] = expf(dots[n] - mx); den += es[n]; }
  float dinv = 1.0f / den;
  float z[4] = { qv[0], qv[1], qv[2], qv[3] };
#pragma unroll
  for (int n = 0; n < N_; ++n) {
    float a = es[n] * dinv;
#pragma unroll
    for (int j = 0; j < 4; ++j) z[j] += a * vs[n][j];
  }
  // LN1: joint (sum, sumsq) reduction, 5 rounds
  float sz = z[0] + z[1] + z[2] + z[3];
  float q2 = z[0]*z[0] + z[1]*z[1] + z[2]*z[2] + z[3]*z[3];
#pragma unroll
  for (int off = 1; off <= 16; off <<= 1) {
    sz += __shfl_xor(sz, off, 64);
    q2 += __shfl_xor(q2, off, 64);
  }
  float mean = sz * (1.0f / DIM_);
  float var = fmaxf(q2 * (1.0f / DIM_) - mean * mean, 0.f);
  float rstd = rsqrtf(var + 1e-5f);
  float4 g4 = *(const float4*)(ln1g + d0);
  float4 b4 = *(const float4*)(ln1b + d0);
  float4 o4;
  o4.x = (z[0] - mean) * rstd * g4.x + b4.x;
  o4.y = (z[1] - mean) * rstd * g4.y + b4.y;
  o4.z = (z[2] - mean) * rstd * g4.z + b4.z;
  o4.w = (z[3] - mean) * rstd * g4.w + b4.w;
  *(float4*)(zln + (size_t)pt * DIM_ + d0) = o4;
}

// ---------------- Kernel D: MLP — INDEPENDENT-WAVE design. 16 px per wave, 64-thr blocks, 1408 blocks ----
// Each wave owns its 16 rows end-to-end; LDS wave-private (hdn hi/lo [16][264] shorts; zo [128][20]
// floats overlays). __syncthreads in a single-wave block is wave-local. LN2 in-register via
// shfl_xor(1,2,4,8). 256 MFMA / 16 px unchanged.
__global__ __launch_bounds__(64) void mlp_kernel(const float* __restrict__ zln,
    const short* __restrict__ w1b, const short* __restrict__ w2b,
    const float* __restrict__ b1, const float* __restrict__ b2,
    const float* __restrict__ ln2g, const float* __restrict__ ln2b,
    float* __restrict__ out) {
  __shared__ __align__(16) char smem[16896];
  short* hh = (short*)smem;             // [16][264] shorts, 8448 B
  short* hl = (short*)(smem + 8448);    // [16][264] shorts, 8448 B
  float* zo = (float*)smem;             // [128][20] floats, 10240 B (overlay, after hdn dead)

  int l = threadIdx.x;                  // 0..63
  int m = l & 15, quad = l >> 4;
  int row0 = blockIdx.x * 16;

  // ---- A1 fragments direct from global zln (hi/lo split) ----
  const float* zr0 = zln + (size_t)(row0 + m) * DIM_;
  short8 A1h[4], A1l[4];
#pragma unroll
  for (int ks = 0; ks < 4; ++ks) {
    float4 xa = *(const float4*)(zr0 + ks * 32 + quad * 8);
    float4 xb = *(const float4*)(zr0 + ks * 32 + quad * 8 + 4);
    float v[8] = {xa.x, xa.y, xa.z, xa.w, xb.x, xb.y, xb.z, xb.w};
#pragma unroll
    for (int j = 0; j < 8; ++j) {
      unsigned short h = f2bf(v[j]);
      A1h[ks][j] = (short)h;
      A1l[ks][j] = (short)f2bf(v[j] - bf2f(h));
    }
  }

  // residual: res[dt][r] = zln[row0 + quad*4 + r][dt*16 + m]
  float res[8][4];
#pragma unroll
  for (int dt = 0; dt < 8; ++dt)
#pragma unroll
    for (int r = 0; r < 4; ++r)
      res[dt][r] = zln[(size_t)(row0 + quad * 4 + r) * DIM_ + dt * 16 + m];

  float b1v[16];
#pragma unroll
  for (int nt = 0; nt < 16; ++nt) b1v[nt] = b1[nt * 16 + m];
  float b2v[8], g2v[8], be2v[8];
#pragma unroll
  for (int dt = 0; dt < 8; ++dt) {
    int d = dt * 16 + m;
    b2v[dt] = b2[d]; g2v[dt] = ln2g[d]; be2v[dt] = ln2b[d];
  }

  // ---- GEMM1: hdn[16px][256] = gelu(zl @ w1 + b1), hi/lo bf16 into wave-private LDS ----
#pragma unroll
  for (int nt = 0; nt < 16; ++nt) {
    f32x4 a = {0.f, 0.f, 0.f, 0.f};
#pragma unroll
    for (int ks = 0; ks < 4; ++ks) {
      short8 Bv = *(const short8*)(w1b + ((size_t)(nt * 4 + ks) * 64 + l) * 8);
      a = __builtin_amdgcn_mfma_f32_16x16x32_bf16(A1h[ks], Bv, a, 0, 0, 0);
      a = __builtin_amdgcn_mfma_f32_16x16x32_bf16(A1l[ks], Bv, a, 0, 0, 0);
    }
#pragma unroll
    for (int r = 0; r < 4; ++r) {
      float hv = a[r] + b1v[nt];
      float g = 0.5f * hv * (1.0f + erff(hv * 0.70710678118654752f));
      unsigned short gh = f2bf(g);
      int addr = (quad * 4 + r) * 264 + nt * 16 + m;
      hh[addr] = (short)gh;
      hl[addr] = (short)f2bf(g - bf2f(gh));
    }
  }
  __syncthreads();   // wave-local: order hdn writes before reads

  // ---- GEMM2: z2[16px][128] = hdn @ w2 ----
  f32x4 acc2[8];
#pragma unroll
  for (int dt = 0; dt < 8; ++dt) acc2[dt] = (f32x4){0.f, 0.f, 0.f, 0.f};
#pragma unroll
  for (int ks2 = 0; ks2 < 8; ++ks2) {
    short8 A2h = *(const short8*)&hh[m * 264 + ks2 * 32 + quad * 8];
    short8 A2l = *(const short8*)&hl[m * 264 + ks2 * 32 + quad * 8];
#pragma unroll
    for (int dt = 0; dt < 8; ++dt) {
      short8 Bv = *(const short8*)(w2b + ((size_t)(dt * 8 + ks2) * 64 + l) * 8);
      acc2[dt] = __builtin_amdgcn_mfma_f32_16x16x32_bf16(A2h, Bv, acc2[dt], 0, 0, 0);
      acc2[dt] = __builtin_amdgcn_mfma_f32_16x16x32_bf16(A2l, Bv, acc2[dt], 0, 0, 0);
    }
  }

  // bias + residual
  float z2[8][4];
#pragma unroll
  for (int dt = 0; dt < 8; ++dt)
#pragma unroll
    for (int r = 0; r < 4; ++r)
      z2[dt][r] = acc2[dt][r] + b2v[dt] + res[dt][r];

  // ---- LN2 in-register: reduce over d = (dt, m); shfl_xor(1,2,4,8) keeps quad invariant ----
  float mean[4], rstd[4];
#pragma unroll
  for (int r = 0; r < 4; ++r) {
    float s = 0.f, q2 = 0.f;
#pragma unroll
    for (int dt = 0; dt < 8; ++dt) { float z = z2[dt][r]; s += z; q2 += z * z; }
#pragma unroll
    for (int off = 1; off <= 8; off <<= 1) {
      s  += __shfl_xor(s,  off, 64);
      q2 += __shfl_xor(q2, off, 64);
    }
    mean[r] = s * (1.0f / 128.0f);
    float var = fmaxf(q2 * (1.0f / 128.0f) - mean[r] * mean[r], 0.f);
    rstd[r] = rsqrtf(var + 1e-5f);
  }
  __syncthreads();   // wave-local: hdn reads done before zo overlay

  // ---- transpose via wave-private zo[128][20], then coalesced float4 stores ----
#pragma unroll
  for (int dt = 0; dt < 8; ++dt)
#pragma unroll
    for (int r = 0; r < 4; ++r) {
      float v = (z2[dt][r] - mean[r]) * rstd[r] * g2v[dt] + be2v[dt];
      zo[(dt * 16 + m) * 20 + quad * 4 + r] = v;
    }
  __syncthreads();   // wave-local

  int bb2 = row0 / P_;
  int p0 = row0 - bb2 * P_;
  float* ob = out + (size_t)bb2 * DIM_ * P_ + p0;
#pragma unroll
  for (int pass = 0; pass < 8; ++pass) {
    int idx = pass * 64 + l;      // 0..511
    int d = idx >> 2, fq = idx & 3;
    float4 v4 = *(float4*)&zo[d * 20 + fq * 4];
    *(float4*)(ob + (size_t)d * P_ + fq * 4) = v4;
  }
}

extern "C" void kernel_launch(void* const* d_in, const int* in_sizes, int n_in,
                              void* d_out, int out_size, void* d_ws, size_t ws_size,
                              hipStream_t stream) {
  const float* feature = (const float*)d_in[0];
  const float* I_src   = (const float*)d_in[1];
  const float* I_tar   = (const float*)d_in[2];
  const float* E       = (const float*)d_in[3];
  const float* dis     = (const float*)d_in[4];
  const float* nrm     = (const float*)d_in[5];
  const float* conv_w  = (const float*)d_in[6];
  const float* bn_g    = (const float*)d_in[7];
  const float* bn_b    = (const float*)d_in[8];
  const float* bn_m    = (const float*)d_in[9];
  const float* bn_v    = (const float*)d_in[10];
  const float* ln1g    = (const float*)d_in[11];
  const float* ln1b    = (const float*)d_in[12];
  const float* ln2g    = (const float*)d_in[13];
  const float* ln2b    = (const float*)d_in[14];
  const float* w1      = (const float*)d_in[15];
  const float* b1      = (const float*)d_in[16];
  const float* w2      = (const float*)d_in[17];
  const float* b2      = (const float*)d_in[18];
  float* out = (float*)d_out;

  float* wsf = (float*)d_ws;
  float* bns = wsf;                   // 128
  float* bnb = wsf + 128;             // 128
  unsigned short* val_t = (unsigned short*)(wsf + 256);          // B*N*P*DIM bf16 (34.6 MB)
  float* zln = (float*)(val_t + (size_t)B_ * N_ * P_ * DIM_);    // B*P*DIM floats
  Samp*  samp = (Samp*)(zln + (size_t)B_ * P_ * DIM_);           // 12*P structs (32B each)
  short* w1b = (short*)(samp + (size_t)B_ * N_ * P_);            // 32768 shorts
  short* w2b = w1b + 32768;                                      // 32768 shorts
  short* cwb = w2b + 32768;                                      // 16384 shorts (conv frags)

  hipLaunchKernelGGL(prep_kernel, dim3(B_ * N_ * UVB + 40), dim3(256), 0, stream,
                     I_src, I_tar, E, dis, nrm, bn_g, bn_b, bn_m, bn_v, w1, w2, conv_w,
                     samp, bns, bnb, w1b, w2b, cwb);
  hipLaunchKernelGGL(conv_kernel, dim3(P_ / 64, B_ * N_), dim3(256), 0, stream,
                     feature, cwb, bns, bnb, val_t);
  hipLaunchKernelGGL(attn_kernel, dim3(B_ * P_ / 8), dim3(256), 0, stream,
                     val_t, samp, ln1g, ln1b, zln);
  hipLaunchKernelGGL(mlp_kernel, dim3(B_ * P_ / 16), dim3(64), 0, stream,
                     zln, w1b, w2b, b1, b2, ln2g, ln2b, out);
}

// Round 8
// 194.435 us; speedup vs baseline: 1.1186x; 1.0860x over previous
//
#include <hip/hip_runtime.h>
#include <hip/hip_bf16.h>
#include <cstdint>
#include <cstddef>

#define B_   2
#define N_   6
#define FD_  128
#define DIM_ 128
#define H_   64
#define W_   176
#define P_   (H_*W_)      // 11264
#define IMGW 704.0
#define IMGH 256.0
#define UVB  8            // uv blocks per (b,n)

struct __align__(16) Samp { float wx, wy; int o00, o01; int o10, o11; int valid, pad; };

typedef __attribute__((ext_vector_type(8))) short short8;
typedef __attribute__((ext_vector_type(4))) float f32x4;

__device__ __forceinline__ float wave_sum(float v) {
#pragma unroll
  for (int off = 32; off > 0; off >>= 1) v += __shfl_xor(v, off, 64);
  return v;
}

// bf16 convert via HW cvt (compiler fuses pairs into v_cvt_pk_bf16_f32)
__device__ __forceinline__ unsigned short f2bf(float f) {
  union { __hip_bfloat16 h; unsigned short u; } c;
  c.h = __float2bfloat16(f);
  return c.u;
}
__device__ __forceinline__ float bf2f(unsigned short s) {
  return __uint_as_float(((unsigned int)s) << 16);
}
__device__ __forceinline__ float bfx(uint2 u, int j) {   // j-th bf16 of an 8B pack (j compile-time)
  unsigned int w = (j < 2) ? u.x : u.y;
  return bf2f((unsigned short)((j & 1) ? (w >> 16) : (w & 0xffffu)));
}

// ---------------- Kernel A: fp64 homography -> sample descriptors; BN fold; weight pre-swizzles ----------------
// blocks 0..95: uv work (8 blocks per bn). blocks 96..135: wprep — 160 frags x 64 lanes, single bf16:
//   f in [0,64): w1b, f in [64,128): w2b, f in [128,160): cwb (conv weights).
__global__ __launch_bounds__(256) void prep_kernel(const float* __restrict__ I_src, const float* __restrict__ I_tar_inv,
                           const float* __restrict__ E, const float* __restrict__ dis,
                           const float* __restrict__ nrm,
                           const float* __restrict__ bn_g, const float* __restrict__ bn_b,
                           const float* __restrict__ bn_m, const float* __restrict__ bn_v,
                           const float* __restrict__ w1, const float* __restrict__ w2,
                           const float* __restrict__ conv_w,
                           Samp* __restrict__ samp, float* __restrict__ bns, float* __restrict__ bnb,
                           short* __restrict__ w1b, short* __restrict__ w2b, short* __restrict__ cwb) {
  int blk = blockIdx.x;
  if (blk >= B_ * N_ * UVB) {
    int tid = (blk - B_ * N_ * UVB) * 256 + threadIdx.x;   // 0..10239
    int f = tid >> 6, l = tid & 63;
    if (f < 64) {
      int nt = f >> 2, ks = f & 3;
      int n = nt * 16 + (l & 15);
      int kb = ks * 32 + (l >> 4) * 8;
#pragma unroll
      for (int j = 0; j < 8; ++j)
        w1b[((size_t)f * 64 + l) * 8 + j] = (short)f2bf(w1[(size_t)(kb + j) * 256 + n]);
    } else if (f < 128) {
      int g = f - 64;
      int nt = g >> 3, ks = g & 7;
      int n = nt * 16 + (l & 15);
      int kb = ks * 32 + (l >> 4) * 8;
#pragma unroll
      for (int j = 0; j < 8; ++j)
        w2b[((size_t)g * 64 + l) * 8 + j] = (short)f2bf(w2[(size_t)(kb + j) * 128 + n]);
    } else {
      int g2 = f - 128;              // 0..31 -> (ot, ks) for conv frags
      int ot = g2 >> 2, ks = g2 & 3;
      int o  = ot * 16 + (l & 15);
      int cb = ks * 32 + (l >> 4) * 8;
#pragma unroll
      for (int j = 0; j < 8; ++j)
        cwb[((size_t)g2 * 64 + l) * 8 + j] = (short)f2bf(conv_w[(size_t)o * FD_ + cb + j]);
    }
    return;
  }
  int bn = blk / UVB;             // 0..11
  int part = blk % UVB;           // 0..7
  int bb = bn / N_;
  if (blk == 0 && threadIdx.x < FD_) {
    int t = threadIdx.x;
    float inv = 1.0f / sqrtf(bn_v[t] + 1e-5f);
    float sc = bn_g[t] * inv;
    bns[t] = sc;
    bnb[t] = bn_b[t] - bn_m[t] * sc;
  }
  const float* Ep = E + bn * 16;
  double R[9], T[3];
#pragma unroll
  for (int i = 0; i < 3; ++i) {
#pragma unroll
    for (int j = 0; j < 3; ++j) R[i*3+j] = (double)Ep[i*4+j];
    T[i] = (double)Ep[i*4+3];
  }
  double dd = (double)dis[bb];
  double M[9];
#pragma unroll
  for (int i = 0; i < 3; ++i)
#pragma unroll
    for (int j = 0; j < 3; ++j)
      M[i*3+j] = R[i*3+j] - T[i] * (double)nrm[bb*3+j] / dd;
  const float* Is = I_src + bn * 9;
  double A[9];
#pragma unroll
  for (int i = 0; i < 3; ++i)
#pragma unroll
    for (int j = 0; j < 3; ++j)
      A[i*3+j] = (double)Is[i*3+0]*M[0+j] + (double)Is[i*3+1]*M[3+j] + (double)Is[i*3+2]*M[6+j];
  const float* It = I_tar_inv + bb * 9;
  double Hm[9];
#pragma unroll
  for (int i = 0; i < 3; ++i)
#pragma unroll
    for (int j = 0; j < 3; ++j)
      Hm[i*3+j] = A[i*3+0]*(double)It[0+j] + A[i*3+1]*(double)It[3+j] + A[i*3+2]*(double)It[6+j];

  const double dx = 1.0 / (double)(W_ - 1);
  const double dy = 1.0 / (double)(H_ - 1);
  for (int p = part * 256 + threadIdx.x; p < P_; p += 256 * UVB) {
    int ii = p / W_;
    int jj = p - ii * W_;
    double xs = (jj == W_ - 1) ? 1.0 : (double)jj * dx;   // np.linspace exact endpoint
    double ys = (ii == H_ - 1) ? 1.0 : (double)ii * dy;
    double px = xs * IMGW;
    double py = ys * IMGH;
    double hx = Hm[0]*px + Hm[1]*py + Hm[2];
    double hy = Hm[3]*px + Hm[4]*py + Hm[5];
    double hz = Hm[6]*px + Hm[7]*py + Hm[8];
    double u = ((hx / hz) / IMGW) * (double)W_;
    double v = ((hy / hz) / IMGH) * (double)H_;
    double x0 = floor(u), y0 = floor(v);
    bool valid = (u >= 0.0) && (u <= (double)(W_ - 1)) && (v >= 0.0) && (v <= (double)(H_ - 1));
    int x0i = min(max((int)x0, 0), W_ - 1);
    int x1i = min(x0i + 1, W_ - 1);
    int y0i = min(max((int)y0, 0), H_ - 1);
    int y1i = min(y0i + 1, H_ - 1);
    Samp s;
    s.wx = (float)(u - x0);
    s.wy = (float)(v - y0);
    s.o00 = (y0i * W_ + x0i) * DIM_;
    s.o01 = (y0i * W_ + x1i) * DIM_;
    s.o10 = (y1i * W_ + x0i) * DIM_;
    s.o11 = (y1i * W_ + x1i) * DIM_;
    s.valid = valid ? 1 : 0;
    s.pad = 0;
    samp[(size_t)bn * P_ + p] = s;
  }
}

// ---------------- Kernel B: BN+ReLU+1x1 conv as bf16 MFMA -> val_t[bn][p][o] in BF16 ----------------
// No-LDS variant: A-fragments loaded DIRECTLY from global feature, BN+ReLU+hi/lo split in registers.
// Weights (cwb, pre-swizzled bf16, 32 KB, L1-resident) as B operand; round-0 store pattern.
__global__ __launch_bounds__(256) void conv_kernel(const float* __restrict__ feature,
    const short* __restrict__ cwb, const float* __restrict__ bns_g, const float* __restrict__ bnb_g,
    unsigned short* __restrict__ val_t) {
  __shared__ float bns_s[FD_], bnb_s[FD_];
  int t = threadIdx.x;
  if (t < FD_) { bns_s[t] = bns_g[t]; bnb_s[t] = bnb_g[t]; }
  __syncthreads();

  int bn = blockIdx.y;
  int p0 = blockIdx.x * 64;
  int lane = t & 63, wv = t >> 6;
  int m = lane & 15, quad = lane >> 4;
  int pw = wv * 16;

  const float* fb = feature + (size_t)bn * FD_ * P_ + p0 + pw + m;

  float xv[4][8];
#pragma unroll
  for (int ks = 0; ks < 4; ++ks)
#pragma unroll
    for (int j = 0; j < 8; ++j) {
      int c = ks * 32 + quad * 8 + j;
      xv[ks][j] = fb[(size_t)c * P_];
    }

  short8 Ah[4], Al[4];
#pragma unroll
  for (int ks = 0; ks < 4; ++ks)
#pragma unroll
    for (int j = 0; j < 8; ++j) {
      int c = ks * 32 + quad * 8 + j;
      float v = fmaxf(xv[ks][j] * bns_s[c] + bnb_s[c], 0.f);
      unsigned short h = f2bf(v);
      Ah[ks][j] = (short)h;
      Al[ks][j] = (short)f2bf(v - bf2f(h));
    }

  f32x4 acc[8];
#pragma unroll
  for (int ot = 0; ot < 8; ++ot) {
    f32x4 a = {0.f, 0.f, 0.f, 0.f};
#pragma unroll
    for (int ks = 0; ks < 4; ++ks) {
      short8 Bv = *(const short8*)(cwb + ((size_t)(ot * 4 + ks) * 64 + lane) * 8);
      a = __builtin_amdgcn_mfma_f32_16x16x32_bf16(Ah[ks], Bv, a, 0, 0, 0);
      a = __builtin_amdgcn_mfma_f32_16x16x32_bf16(Al[ks], Bv, a, 0, 0, 0);
    }
    acc[ot] = a;
  }

  unsigned short* vb = val_t + ((size_t)bn * P_ + p0 + pw + quad * 4) * DIM_ + m;
#pragma unroll
  for (int ot = 0; ot < 8; ++ot)
#pragma unroll
    for (int r = 0; r < 4; ++r)
      vb[(size_t)r * DIM_ + ot * 16] = f2bf(acc[ot][r]);
}

// ---------------- Kernel C: bilinear attention + LN1 — 2 px per wave, 32-lane groups, 4 dims/lane ----
__global__ __launch_bounds__(256) void attn_kernel(const unsigned short* __restrict__ val_t,
    const Samp* __restrict__ samp,
    const float* __restrict__ ln1g, const float* __restrict__ ln1b,
    float* __restrict__ zln) {
  int lane = threadIdx.x & 63;
  int wv = threadIdx.x >> 6;
  int half = lane >> 5;
  int sl = lane & 31;
  int bid = blockIdx.x;
  int newbid = (bid & 7) * (gridDim.x >> 3) + (bid >> 3);   // XCD swizzle (grid % 8 == 0)
  int pt = newbid * 8 + wv * 2 + half;
  int bb = pt / P_;
  int p = pt - bb * P_;
  int d0 = sl << 2;               // dims d0..d0+3

  uint2 uq = *(const uint2*)(val_t + ((size_t)(bb * N_) * P_ + p) * DIM_ + d0);
  float qv[4] = { bfx(uq, 0), bfx(uq, 1), bfx(uq, 2), bfx(uq, 3) };
  float qss = qv[0]*qv[0] + qv[1]*qv[1] + qv[2]*qv[2] + qv[3]*qv[3];
#pragma unroll
  for (int off = 1; off <= 16; off <<= 1) qss += __shfl_xor(qss, off, 64);
  float qinv = 1.0f / fmaxf(sqrtf(qss), 1e-12f);

  float dots[N_], vs[N_][4];
#pragma unroll
  for (int n = 0; n < N_; ++n) {
    Samp s = samp[(size_t)(bb * N_ + n) * P_ + p];
    const unsigned short* base = val_t + (size_t)(bb * N_ + n) * P_ * DIM_ + d0;
    uint2 u00 = *(const uint2*)(base + s.o00);
    uint2 u01 = *(const uint2*)(base + s.o01);
    uint2 u10 = *(const uint2*)(base + s.o10);
    uint2 u11 = *(const uint2*)(base + s.o11);
    float wx = s.wx, wy = s.wy;
    float w00 = (1.0f - wx) * (1.0f - wy), w01 = wx * (1.0f - wy);
    float w10 = (1.0f - wx) * wy,          w11 = wx * wy;
    float ss = 0.f, du = 0.f;
#pragma unroll
    for (int j = 0; j < 4; ++j) {
      float v = bfx(u00, j) * w00 + bfx(u01, j) * w01 + bfx(u10, j) * w10 + bfx(u11, j) * w11;
      vs[n][j] = v;
      ss += v * v;
      du += qv[j] * v;
    }
#pragma unroll
    for (int off = 1; off <= 16; off <<= 1) {
      ss += __shfl_xor(ss, off, 64);
      du += __shfl_xor(du, off, 64);
    }
    float kinv = 1.0f / fmaxf(sqrtf(ss), 1e-12f);
    dots[n] = s.valid ? (du * kinv * qinv) : 0.0f;
  }
  float mx = dots[0];
#pragma unroll
  for (int n = 1; n < N_; ++n) mx = fmaxf(mx, dots[n]);
  float es[N_], den = 0.f;
#pragma unroll
  for (int n = 0; n < N_; ++n) { es[n] = expf(dots[n] - mx); den += es[n]; }
  float dinv = 1.0f / den;
  float z[4] = { qv[0], qv[1], qv[2], qv[3] };
#pragma unroll
  for (int n = 0; n < N_; ++n) {
    float a = es[n] * dinv;
#pragma unroll
    for (int j = 0; j < 4; ++j) z[j] += a * vs[n][j];
  }
  // LN1: joint (sum, sumsq) reduction, 5 rounds
  float sz = z[0] + z[1] + z[2] + z[3];
  float q2 = z[0]*z[0] + z[1]*z[1] + z[2]*z[2] + z[3]*z[3];
#pragma unroll
  for (int off = 1; off <= 16; off <<= 1) {
    sz += __shfl_xor(sz, off, 64);
    q2 += __shfl_xor(q2, off, 64);
  }
  float mean = sz * (1.0f / DIM_);
  float var = fmaxf(q2 * (1.0f / DIM_) - mean * mean, 0.f);
  float rstd = rsqrtf(var + 1e-5f);
  float4 g4 = *(const float4*)(ln1g + d0);
  float4 b4 = *(const float4*)(ln1b + d0);
  float4 o4;
  o4.x = (z[0] - mean) * rstd * g4.x + b4.x;
  o4.y = (z[1] - mean) * rstd * g4.y + b4.y;
  o4.z = (z[2] - mean) * rstd * g4.z + b4.z;
  o4.w = (z[3] - mean) * rstd * g4.w + b4.w;
  *(float4*)(zln + (size_t)pt * DIM_ + d0) = o4;
}

// ---------------- Kernel D: MLP — 4 waves per 16-px tile (intra-tile split), 1408 blocks x 256 thr ----
// Wave ng owns: GEMM1 nt ∈ {ng*4..ng*4+3} (N-split, 32 MFMA) -> shared hdn; GEMM2 dt ∈ {ng*2, ng*2+1}
// (N-split, full K, 32 MFMA, no acc reduction). 5632 waves total (5.5/SIMD vs 1.375 before).
// 3 barriers: B1 hdn ready, B2 LN2 partials, B3 zo transpose.
__global__ __launch_bounds__(256) void mlp_kernel(const float* __restrict__ zln,
    const short* __restrict__ w1b, const short* __restrict__ w2b,
    const float* __restrict__ b1, const float* __restrict__ b2,
    const float* __restrict__ ln2g, const float* __restrict__ ln2b,
    float* __restrict__ out) {
  __shared__ __align__(16) char smem[17408];
  short* hh = (short*)smem;              // [16][264] shorts, 8448 B
  short* hl = (short*)(smem + 8448);     // [16][264] shorts, 8448 B
  float* pbuf = (float*)(smem + 16896);  // 128 floats (sums + sumsq)
  float* zo = (float*)smem;              // [128][20] floats overlay (after hdn dead)

  int t = threadIdx.x;
  int l = t & 63, ng = t >> 6;           // wave 0..3
  int m = l & 15, quad = l >> 4;
  int row0 = blockIdx.x * 16;

  // ---- A1 fragments direct from global zln (each wave redundantly; 8KB, L2-hot) ----
  const float* zr0 = zln + (size_t)(row0 + m) * DIM_;
  short8 A1h[4], A1l[4];
#pragma unroll
  for (int ks = 0; ks < 4; ++ks) {
    float4 xa = *(const float4*)(zr0 + ks * 32 + quad * 8);
    float4 xb = *(const float4*)(zr0 + ks * 32 + quad * 8 + 4);
    float v[8] = {xa.x, xa.y, xa.z, xa.w, xb.x, xb.y, xb.z, xb.w};
#pragma unroll
    for (int j = 0; j < 8; ++j) {
      unsigned short h = f2bf(v[j]);
      A1h[ks][j] = (short)h;
      A1l[ks][j] = (short)f2bf(v[j] - bf2f(h));
    }
  }

  // per-wave constants
  float b1v[4];
#pragma unroll
  for (int i = 0; i < 4; ++i) b1v[i] = b1[(ng * 4 + i) * 16 + m];
  float res[2][4], b2v[2], g2v[2], be2v[2];
#pragma unroll
  for (int e = 0; e < 2; ++e) {
    int dt = ng * 2 + e;
    int d = dt * 16 + m;
    b2v[e] = b2[d]; g2v[e] = ln2g[d]; be2v[e] = ln2b[d];
#pragma unroll
    for (int r = 0; r < 4; ++r)
      res[e][r] = zln[(size_t)(row0 + quad * 4 + r) * DIM_ + dt * 16 + m];
  }

  // ---- GEMM1: this wave's 4 hidden tiles -> shared hdn ----
#pragma unroll
  for (int i = 0; i < 4; ++i) {
    int nt = ng * 4 + i;
    f32x4 a = {0.f, 0.f, 0.f, 0.f};
#pragma unroll
    for (int ks = 0; ks < 4; ++ks) {
      short8 Bv = *(const short8*)(w1b + ((size_t)(nt * 4 + ks) * 64 + l) * 8);
      a = __builtin_amdgcn_mfma_f32_16x16x32_bf16(A1h[ks], Bv, a, 0, 0, 0);
      a = __builtin_amdgcn_mfma_f32_16x16x32_bf16(A1l[ks], Bv, a, 0, 0, 0);
    }
#pragma unroll
    for (int r = 0; r < 4; ++r) {
      float hv = a[r] + b1v[i];
      float g = 0.5f * hv * (1.0f + erff(hv * 0.70710678118654752f));
      unsigned short gh = f2bf(g);
      int addr = (quad * 4 + r) * 264 + nt * 16 + m;
      hh[addr] = (short)gh;
      hl[addr] = (short)f2bf(g - bf2f(gh));
    }
  }
  __syncthreads();   // B1: all hdn writes visible

  // ---- GEMM2: this wave's 2 output dt, full K=256 ----
  f32x4 acc2[2];
  acc2[0] = (f32x4){0.f, 0.f, 0.f, 0.f};
  acc2[1] = (f32x4){0.f, 0.f, 0.f, 0.f};
#pragma unroll
  for (int ks2 = 0; ks2 < 8; ++ks2) {
    short8 A2h = *(const short8*)&hh[m * 264 + ks2 * 32 + quad * 8];
    short8 A2l = *(const short8*)&hl[m * 264 + ks2 * 32 + quad * 8];
#pragma unroll
    for (int e = 0; e < 2; ++e) {
      int g = (ng * 2 + e) * 8 + ks2;
      short8 Bv = *(const short8*)(w2b + ((size_t)g * 64 + l) * 8);
      acc2[e] = __builtin_amdgcn_mfma_f32_16x16x32_bf16(A2h, Bv, acc2[e], 0, 0, 0);
      acc2[e] = __builtin_amdgcn_mfma_f32_16x16x32_bf16(A2l, Bv, acc2[e], 0, 0, 0);
    }
  }

  // bias + residual
  float z2[2][4];
#pragma unroll
  for (int e = 0; e < 2; ++e)
#pragma unroll
    for (int r = 0; r < 4; ++r)
      z2[e][r] = acc2[e][r] + b2v[e] + res[e][r];

  // ---- LN2: per-wave partials (sum over its 32 dims) -> pbuf; one barrier ----
  float ps[4], pq2[4];
#pragma unroll
  for (int r = 0; r < 4; ++r) {
    float s = z2[0][r] + z2[1][r];
    float q2 = z2[0][r]*z2[0][r] + z2[1][r]*z2[1][r];
#pragma unroll
    for (int off = 1; off <= 8; off <<= 1) {
      s  += __shfl_xor(s,  off, 64);
      q2 += __shfl_xor(q2, off, 64);
    }
    ps[r] = s; pq2[r] = q2;
  }
  if (m == 0) {
#pragma unroll
    for (int r = 0; r < 4; ++r) {
      pbuf[ng * 16 + quad * 4 + r]      = ps[r];
      pbuf[64 + ng * 16 + quad * 4 + r] = pq2[r];
    }
  }
  __syncthreads();   // B2 (also: all hdn reads complete before zo overlay below)

  float mean[4], rstd[4];
#pragma unroll
  for (int r = 0; r < 4; ++r) {
    int px = quad * 4 + r;
    float s = pbuf[px] + pbuf[16 + px] + pbuf[32 + px] + pbuf[48 + px];
    float q = pbuf[64 + px] + pbuf[80 + px] + pbuf[96 + px] + pbuf[112 + px];
    mean[r] = s * (1.0f / 128.0f);
    float var = fmaxf(q * (1.0f / 128.0f) - mean[r] * mean[r], 0.f);
    rstd[r] = rsqrtf(var + 1e-5f);
  }

  // ---- normalize + transpose via zo (overlays hdn region; pbuf region disjoint) ----
#pragma unroll
  for (int e = 0; e < 2; ++e) {
    int dt = ng * 2 + e;
#pragma unroll
    for (int r = 0; r < 4; ++r) {
      float v = (z2[e][r] - mean[r]) * rstd[r] * g2v[e] + be2v[e];
      zo[(dt * 16 + m) * 20 + quad * 4 + r] = v;
    }
  }
  __syncthreads();   // B3

  // coalesced transposed store: out[b][d][p], 16 px per block
  int bb2 = row0 / P_;
  int p0 = row0 - bb2 * P_;
  float* ob = out + (size_t)bb2 * DIM_ * P_ + p0;
#pragma unroll
  for (int pass = 0; pass < 2; ++pass) {
    int idx = pass * 256 + t;     // 0..511
    int d = idx >> 2, fq = idx & 3;
    float4 v4 = *(float4*)&zo[d * 20 + fq * 4];
    *(float4*)(ob + (size_t)d * P_ + fq * 4) = v4;
  }
}

extern "C" void kernel_launch(void* const* d_in, const int* in_sizes, int n_in,
                              void* d_out, int out_size, void* d_ws, size_t ws_size,
                              hipStream_t stream) {
  const float* feature = (const float*)d_in[0];
  const float* I_src   = (const float*)d_in[1];
  const float* I_tar   = (const float*)d_in[2];
  const float* E       = (const float*)d_in[3];
  const float* dis     = (const float*)d_in[4];
  const float* nrm     = (const float*)d_in[5];
  const float* conv_w  = (const float*)d_in[6];
  const float* bn_g    = (const float*)d_in[7];
  const float* bn_b    = (const float*)d_in[8];
  const float* bn_m    = (const float*)d_in[9];
  const float* bn_v    = (const float*)d_in[10];
  const float* ln1g    = (const float*)d_in[11];
  const float* ln1b    = (const float*)d_in[12];
  const float* ln2g    = (const float*)d_in[13];
  const float* ln2b    = (const float*)d_in[14];
  const float* w1      = (const float*)d_in[15];
  const float* b1      = (const float*)d_in[16];
  const float* w2      = (const float*)d_in[17];
  const float* b2      = (const float*)d_in[18];
  float* out = (float*)d_out;

  float* wsf = (float*)d_ws;
  float* bns = wsf;                   // 128
  float* bnb = wsf + 128;             // 128
  unsigned short* val_t = (unsigned short*)(wsf + 256);          // B*N*P*DIM bf16 (34.6 MB)
  float* zln = (float*)(val_t + (size_t)B_ * N_ * P_ * DIM_);    // B*P*DIM floats
  Samp*  samp = (Samp*)(zln + (size_t)B_ * P_ * DIM_);           // 12*P structs (32B each)
  short* w1b = (short*)(samp + (size_t)B_ * N_ * P_);            // 32768 shorts
  short* w2b = w1b + 32768;                                      // 32768 shorts
  short* cwb = w2b + 32768;                                      // 16384 shorts (conv frags)

  hipLaunchKernelGGL(prep_kernel, dim3(B_ * N_ * UVB + 40), dim3(256), 0, stream,
                     I_src, I_tar, E, dis, nrm, bn_g, bn_b, bn_m, bn_v, w1, w2, conv_w,
                     samp, bns, bnb, w1b, w2b, cwb);
  hipLaunchKernelGGL(conv_kernel, dim3(P_ / 64, B_ * N_), dim3(256), 0, stream,
                     feature, cwb, bns, bnb, val_t);
  hipLaunchKernelGGL(attn_kernel, dim3(B_ * P_ / 8), dim3(256), 0, stream,
                     val_t, samp, ln1g, ln1b, zln);
  hipLaunchKernelGGL(mlp_kernel, dim3(B_ * P_ / 16), dim3(256), 0, stream,
                     zln, w1b, w2b, b1, b2, ln2g, ln2b, out);
}